// Round 1
// baseline (5625.064 us; speedup 1.0000x reference)
//
#include <hip/hip_runtime.h>
#include <hip/hip_bf16.h>
#include <math.h>

#define DIM 128

// ---------------- gather rows from embedding table ----------------
__global__ void gather_rows(const float* __restrict__ table, const int* __restrict__ idx,
                            float* __restrict__ dst, int n) {
  int i = blockIdx.x * blockDim.x + threadIdx.x;   // over n*32 float4s
  int total = n * 32;
  if (i >= total) return;
  int r = i >> 5, c = i & 31;
  const float4* src = (const float4*)table + (size_t)idx[r] * 32 + c;
  ((float4*)dst)[i] = *src;
}

// ---------------- generic NT GEMM: C[n][m] = f(dot(A[n],B[m]) + bias[m]) * adj[n][m] ----------------
// A: [N][K] row-major, B: [M][K] row-major. Tile 64x64, 256 threads, 4x4 per thread.
template<bool RELU, bool HASBIAS, bool HASADJ>
__global__ __launch_bounds__(256) void gemm_nt(
    const float* __restrict__ A, const float* __restrict__ B,
    float* __restrict__ C, int ldc, int K,
    const float* __restrict__ bias,
    const float* __restrict__ adj, int ldadj)
{
  __shared__ float As[64][17];
  __shared__ float Bs[64][17];
  int tid = threadIdx.x;
  int tx = tid & 15, ty = tid >> 4;
  int rowBase = blockIdx.y * 64, colBase = blockIdx.x * 64;
  int lr = tid >> 2, lk = (tid & 3) * 4;
  float acc[4][4] = {};
  for (int k0 = 0; k0 < K; k0 += 16) {
    float4 av = *(const float4*)&A[(size_t)(rowBase + lr) * K + k0 + lk];
    float4 bv = *(const float4*)&B[(size_t)(colBase + lr) * K + k0 + lk];
    As[lr][lk+0]=av.x; As[lr][lk+1]=av.y; As[lr][lk+2]=av.z; As[lr][lk+3]=av.w;
    Bs[lr][lk+0]=bv.x; Bs[lr][lk+1]=bv.y; Bs[lr][lk+2]=bv.z; Bs[lr][lk+3]=bv.w;
    __syncthreads();
#pragma unroll
    for (int kk = 0; kk < 16; ++kk) {
      float a0=As[ty*4+0][kk], a1=As[ty*4+1][kk], a2=As[ty*4+2][kk], a3=As[ty*4+3][kk];
      float b0=Bs[tx*4+0][kk], b1=Bs[tx*4+1][kk], b2=Bs[tx*4+2][kk], b3=Bs[tx*4+3][kk];
      acc[0][0]+=a0*b0; acc[0][1]+=a0*b1; acc[0][2]+=a0*b2; acc[0][3]+=a0*b3;
      acc[1][0]+=a1*b0; acc[1][1]+=a1*b1; acc[1][2]+=a1*b2; acc[1][3]+=a1*b3;
      acc[2][0]+=a2*b0; acc[2][1]+=a2*b1; acc[2][2]+=a2*b2; acc[2][3]+=a2*b3;
      acc[3][0]+=a3*b0; acc[3][1]+=a3*b1; acc[3][2]+=a3*b2; acc[3][3]+=a3*b3;
    }
    __syncthreads();
  }
  int row = rowBase + ty*4, col = colBase + tx*4;
#pragma unroll
  for (int i = 0; i < 4; ++i) {
    float aj[4] = {1.f,1.f,1.f,1.f};
    if (HASADJ) {
      float4 adjv = *(const float4*)&adj[(size_t)(row+i)*ldadj + col];
      aj[0]=adjv.x; aj[1]=adjv.y; aj[2]=adjv.z; aj[3]=adjv.w;
    }
    float v[4];
#pragma unroll
    for (int j = 0; j < 4; ++j) {
      float x = acc[i][j];
      if (HASBIAS) x += bias[col+j];
      if (HASADJ) x *= aj[j];
      if (RELU) x = fmaxf(x, 0.f);
      v[j] = x;
    }
    float* cp = &C[(size_t)(row+i)*ldc + col];   // 8B-aligned even at d_out+2
    *(float2*)cp = make_float2(v[0], v[1]);
    *(float2*)(cp+2) = make_float2(v[2], v[3]);
  }
}

// ---------------- row reduction: abs-sum (with eps floor) or mean ----------------
template<bool ABS>
__global__ void row_reduce(const float* __restrict__ W, int ld, int M,
                           float* __restrict__ out, float p /*eps or 1/M*/) {
  int n = blockIdx.x;
  const float* row = W + (size_t)n * ld;
  float s = 0;
  for (int m = threadIdx.x; m < M; m += 256) {
    float v = row[m];
    s += ABS ? fabsf(v) : v;
  }
  __shared__ float red[256];
  red[threadIdx.x] = s; __syncthreads();
  for (int k = 128; k > 0; k >>= 1) {
    if (threadIdx.x < k) red[threadIdx.x] += red[threadIdx.x + k];
    __syncthreads();
  }
  if (threadIdx.x == 0) out[n] = ABS ? fmaxf(red[0], p) : red[0] * p;
}

__global__ void col_mean(const float* __restrict__ W, int ld, int N,
                         float* __restrict__ out, float inv) {
  int m = blockIdx.x * blockDim.x + threadIdx.x;
  float s = 0;
  for (int n = 0; n < N; ++n) s += W[(size_t)n * ld + m];
  out[m] = s * inv;
}

// ---------------- attn @ hs with K-split: pt[kc][n][d] = sum_{m in chunk kc} attn[n][m]*hs[m][d] ----------------
__global__ __launch_bounds__(256) void attn_av(
    const float* __restrict__ attn, int ld,
    const float* __restrict__ hs, float* __restrict__ pt,
    int chunk, int N)
{
  int r0 = blockIdx.x * 32;
  int kc = blockIdx.y;
  int m0 = kc * chunk;
  __shared__ float Hs[32][DIM];
  __shared__ float As[32][33];
  int tid = threadIdx.x;
  int tx = tid & 31, ry = tid >> 5;
  float acc[4][4] = {};
  for (int mt = 0; mt < chunk; mt += 32) {
#pragma unroll
    for (int q = 0; q < 4; ++q) {
      int f = q * 256 + tid; int hr = f >> 5, hc = (f & 31) * 4;
      *(float4*)&Hs[hr][hc] = *(const float4*)&hs[(size_t)(m0 + mt + hr) * DIM + hc];
    }
    {
      int ar = tid >> 3, ac = (tid & 7) * 4;
      const float* src = &attn[(size_t)(r0 + ar) * ld + m0 + mt + ac];
      float2 u = *(const float2*)src; float2 w = *(const float2*)(src + 2);
      As[ar][ac] = u.x; As[ar][ac+1] = u.y; As[ar][ac+2] = w.x; As[ar][ac+3] = w.y;
    }
    __syncthreads();
#pragma unroll
    for (int mm = 0; mm < 32; ++mm) {
      float4 h4 = *(const float4*)&Hs[mm][tx * 4];
      float a0 = As[ry*4+0][mm], a1 = As[ry*4+1][mm], a2 = As[ry*4+2][mm], a3 = As[ry*4+3][mm];
      acc[0][0]+=a0*h4.x; acc[0][1]+=a0*h4.y; acc[0][2]+=a0*h4.z; acc[0][3]+=a0*h4.w;
      acc[1][0]+=a1*h4.x; acc[1][1]+=a1*h4.y; acc[1][2]+=a1*h4.z; acc[1][3]+=a1*h4.w;
      acc[2][0]+=a2*h4.x; acc[2][1]+=a2*h4.y; acc[2][2]+=a2*h4.z; acc[2][3]+=a2*h4.w;
      acc[3][0]+=a3*h4.x; acc[3][1]+=a3*h4.y; acc[3][2]+=a3*h4.z; acc[3][3]+=a3*h4.w;
    }
    __syncthreads();
  }
#pragma unroll
  for (int i = 0; i < 4; ++i) {
    float4 v = make_float4(acc[i][0], acc[i][1], acc[i][2], acc[i][3]);
    *(float4*)&pt[((size_t)kc * N + r0 + ry*4 + i) * DIM + tx*4] = v;
  }
}

// xs[n][d] += (sum_kc pt[kc][n][d]) / denom[n]
__global__ void axpy_reduce(const float* __restrict__ pt, const float* __restrict__ denom,
                            float* __restrict__ xs, int total) {
  int i = blockIdx.x * blockDim.x + threadIdx.x;
  if (i >= total) return;
  float s = 0;
#pragma unroll
  for (int k = 0; k < 8; ++k) s += pt[(size_t)k * total + i];
  xs[i] += s / denom[i >> 7];
}

__global__ void add_vec(const float* __restrict__ a, const float* __restrict__ b,
                        float* __restrict__ o, int n) {
  int i = blockIdx.x * blockDim.x + threadIdx.x;
  if (i < n) o[i] = a[i] + b[i];
}

// ---------------- bidirectional LSTM (one block per direction) ----------------
__global__ __launch_bounds__(512) void lstm_kernel(
    const float* __restrict__ Whh,   // [2][512][128]
    const float* __restrict__ Wx,    // [2][M][512]  (x@Wih.T + bih + bhh precomputed)
    float* __restrict__ xs_rnn,      // [M][256]  (stores relu(h))
    int M)
{
  int dir = blockIdx.x;
  int j = threadIdx.x;                 // 0..511  (z row)
  __shared__ float h_lds[DIM];
  __shared__ float act[512];
  float4 w[32];
  const float4* wrow = (const float4*)(Whh + ((size_t)dir * 512 + j) * DIM);
#pragma unroll
  for (int r = 0; r < 32; ++r) w[r] = wrow[r];
  float c = 0.f;
  if (j < DIM) h_lds[j] = 0.f;
  __syncthreads();
  const float* WxD = Wx + (size_t)dir * M * 512;
  int g = j >> 7;
  for (int s = 0; s < M; ++s) {
    int t = dir ? (M - 1 - s) : s;
    float wx = WxD[(size_t)t * 512 + j];      // overlaps with dot below
    float a0 = 0, a1 = 0, a2 = 0, a3 = 0;
#pragma unroll
    for (int r = 0; r < 32; ++r) {
      float4 h4 = ((const float4*)h_lds)[r];  // LDS broadcast
      a0 += w[r].x * h4.x; a1 += w[r].y * h4.y;
      a2 += w[r].z * h4.z; a3 += w[r].w * h4.w;
    }
    float z = (a0 + a1) + (a2 + a3) + wx;
    float av;
    if (g == 2) av = tanhf(z);
    else        av = 1.f / (1.f + __expf(-z));
    act[j] = av;
    __syncthreads();
    if (j < DIM) {
      float iv = act[j], fv = act[DIM + j], gv = act[2*DIM + j], ov = act[3*DIM + j];
      c = fv * c + iv * gv;
      float hv = ov * tanhf(c);
      h_lds[j] = hv;
      xs_rnn[(size_t)t * (2*DIM) + dir * DIM + j] = fmaxf(hv, 0.f);
    }
    __syncthreads();
  }
}

// ---------------- weighted mean pooling: out[d] = (1/n) sum_r wv[r]*mat[r][d] ----------------
__global__ void pool_vec(const float* __restrict__ mat, const float* __restrict__ wv,
                         int n, float* __restrict__ out, float inv) {
  int t = threadIdx.x; int g = t >> 7, d = t & 127;
  float acc = 0;
  for (int r = g; r < n; r += 8) acc += wv[r] * mat[(size_t)r * DIM + d];
  __shared__ float red[1024];
  red[t] = acc; __syncthreads();
  if (g == 0) {
    float s = acc;
#pragma unroll
    for (int k = 1; k < 8; ++k) s += red[k * 128 + d];
    out[d] = s * inv;
  }
}

// ---------------- output MLP (tiny, one block) ----------------
__global__ void mlp_kernel(const float* __restrict__ cvec, const float* __restrict__ pvec,
                           const float* __restrict__ Wo, const float* __restrict__ bo,
                           const float* __restrict__ Wi, const float* __restrict__ bi,
                           float* __restrict__ out) {
  __shared__ float buf0[256], buf1[256];
  int t = threadIdx.x;
  buf0[t] = (t < 128) ? cvec[t] : pvec[t - 128];
  __syncthreads();
  {
    const float* W = Wo;                 // layer 0
    float s = bo[t];
    for (int v = 0; v < 256; ++v) s += W[t * 256 + v] * buf0[v];
    buf1[t] = fmaxf(s, 0.f);
  }
  __syncthreads();
  {
    const float* W = Wo + 256 * 256;     // layer 1
    float s = bo[256 + t];
    for (int v = 0; v < 256; ++v) s += W[t * 256 + v] * buf1[v];
    buf0[t] = fmaxf(s, 0.f);
  }
  __syncthreads();
  if (t < 2) {
    float s = bi[t];
    for (int v = 0; v < 256; ++v) s += Wi[t * 256 + v] * buf0[v];
    out[t] = s;
  }
}

extern "C" void kernel_launch(void* const* d_in, const int* in_sizes, int n_in,
                              void* d_out, int out_size, void* d_ws, size_t ws_size,
                              hipStream_t stream) {
  const int*   fingerprints = (const int*)d_in[0];
  const float* adjacency    = (const float*)d_in[1];
  const int*   words        = (const int*)d_in[2];
  const float* emb_fp       = (const float*)d_in[3];
  const float* emb_word     = (const float*)d_in[4];
  const float* Wg  = (const float*)d_in[5];
  const float* bg  = (const float*)d_in[6];
  const float* Wih = (const float*)d_in[7];
  const float* Whh = (const float*)d_in[8];
  const float* bih = (const float*)d_in[9];
  const float* bhh = (const float*)d_in[10];
  const float* Wc  = (const float*)d_in[11];
  const float* bc  = (const float*)d_in[12];
  const float* Wp  = (const float*)d_in[13];
  const float* bp  = (const float*)d_in[14];
  const float* Wo  = (const float*)d_in[15];
  const float* bo  = (const float*)d_in[16];
  const float* Wi  = (const float*)d_in[17];
  const float* bi  = (const float*)d_in[18];

  const int N = in_sizes[0];
  const int M = in_sizes[2];
  const int LGAT = in_sizes[5] / (DIM * DIM);

  float* out  = (float*)d_out;
  float* attn = out + 2;            // [N][M]: scratch during GAT, final `weights` at end

  float* ws = (float*)d_ws;
  size_t off = 0;
  auto alloc = [&](size_t nf) { float* p = ws + off; off += (nf + 3) & ~(size_t)3; return p; };
  float* xs     = alloc((size_t)N * DIM);
  float* hs     = alloc((size_t)N * DIM);
  float* wvb    = alloc((size_t)M * DIM);
  float* denom  = alloc(N);
  float* pt     = alloc((size_t)8 * N * DIM);    // K-split partials; aliased as Wx afterwards
  float* Wx     = pt;                            // [2][M][512] — GAT is done before LSTM precompute
  float* xs_rnn = alloc((size_t)M * 2 * DIM);
  float* hp     = alloc((size_t)M * DIM);
  float* hmat   = alloc((size_t)N * DIM);
  float* bsum   = alloc(1024);
  float* wcomp  = alloc(N);
  float* wprot  = alloc(M);
  float* cvec   = alloc(DIM);
  float* pvec   = alloc(DIM);
  (void)ws_size; (void)n_in; (void)out_size;

  // ---- embeddings ----
  gather_rows<<<(N * 32 + 255) / 256, 256, 0, stream>>>(emb_fp, fingerprints, xs, N);
  gather_rows<<<(M * 32 + 255) / 256, 256, 0, stream>>>(emb_word, words, wvb, M);

  // ---- GAT layers ----
  for (int l = 0; l < LGAT; ++l) {
    gemm_nt<true, true, false><<<dim3(DIM / 64, N / 64), 256, 0, stream>>>(
        xs, Wg + (size_t)l * DIM * DIM, hs, DIM, DIM, bg + l * DIM, nullptr, 0);
    gemm_nt<false, false, true><<<dim3(M / 64, N / 64), 256, 0, stream>>>(
        hs, hs, attn, M, DIM, nullptr, adjacency, M);
    row_reduce<true><<<N, 256, 0, stream>>>(attn, M, M, denom, 1e-12f);
    attn_av<<<dim3(N / 32, 8), 256, 0, stream>>>(attn, M, hs, pt, M / 8, N);
    axpy_reduce<<<(N * DIM) / 256, 256, 0, stream>>>(pt, denom, xs, N * DIM);
  }

  // ---- LSTM precompute + run ----
  add_vec<<<4, 256, 0, stream>>>(bih, bhh, bsum, 1024);
  for (int d = 0; d < 2; ++d) {
    gemm_nt<false, true, false><<<dim3(512 / 64, M / 64), 256, 0, stream>>>(
        wvb, Wih + (size_t)d * 512 * DIM, Wx + (size_t)d * M * 512, 512, DIM,
        bsum + d * 512, nullptr, 0);
  }
  lstm_kernel<<<2, 512, 0, stream>>>(Whh, Wx, xs_rnn, M);

  // ---- cross-attention pooling ----
  gemm_nt<true, true, false><<<dim3(DIM / 64, M / 64), 256, 0, stream>>>(
      xs_rnn, Wp, hp, DIM, 2 * DIM, bp, nullptr, 0);
  gemm_nt<true, true, false><<<dim3(DIM / 64, N / 64), 256, 0, stream>>>(
      xs, Wc, hmat, DIM, DIM, bc, nullptr, 0);
  gemm_nt<false, false, false><<<dim3(M / 64, N / 64), 256, 0, stream>>>(
      hmat, hp, attn, M, DIM, nullptr, nullptr, 0);   // final `weights` output
  row_reduce<false><<<N, 256, 0, stream>>>(attn, M, M, wcomp, 1.f / (float)M);
  col_mean<<<M / 256, 256, 0, stream>>>(attn, M, N, wprot, 1.f / (float)N);
  pool_vec<<<1, 1024, 0, stream>>>(hmat, wcomp, N, cvec, 1.f / (float)N);
  pool_vec<<<1, 1024, 0, stream>>>(hp, wprot, M, pvec, 1.f / (float)M);

  // ---- output MLP ----
  mlp_kernel<<<1, 256, 0, stream>>>(cvec, pvec, Wo, bo, Wi, bi, out);
}

// Round 2
// 4546.700 us; speedup vs baseline: 1.2372x; 1.2372x over previous
//
#include <hip/hip_runtime.h>
#include <hip/hip_bf16.h>
#include <math.h>

#define DIM 128

// ---------------- gather rows from embedding table ----------------
__global__ void gather_rows(const float* __restrict__ table, const int* __restrict__ idx,
                            float* __restrict__ dst, int n) {
  int i = blockIdx.x * blockDim.x + threadIdx.x;   // over n*32 float4s
  int total = n * 32;
  if (i >= total) return;
  int r = i >> 5, c = i & 31;
  const float4* src = (const float4*)table + (size_t)idx[r] * 32 + c;
  ((float4*)dst)[i] = *src;
}

// ---------------- generic NT GEMM: C[n][m] = f(dot(A[n],B[m]) + bias[m]) * adj[n][m] ----------------
template<bool RELU, bool HASBIAS, bool HASADJ>
__global__ __launch_bounds__(256) void gemm_nt(
    const float* __restrict__ A, const float* __restrict__ B,
    float* __restrict__ C, int ldc, int K,
    const float* __restrict__ bias,
    const float* __restrict__ adj, int ldadj)
{
  __shared__ float As[64][17];
  __shared__ float Bs[64][17];
  int tid = threadIdx.x;
  int tx = tid & 15, ty = tid >> 4;
  int rowBase = blockIdx.y * 64, colBase = blockIdx.x * 64;
  int lr = tid >> 2, lk = (tid & 3) * 4;
  float acc[4][4] = {};
  for (int k0 = 0; k0 < K; k0 += 16) {
    float4 av = *(const float4*)&A[(size_t)(rowBase + lr) * K + k0 + lk];
    float4 bv = *(const float4*)&B[(size_t)(colBase + lr) * K + k0 + lk];
    As[lr][lk+0]=av.x; As[lr][lk+1]=av.y; As[lr][lk+2]=av.z; As[lr][lk+3]=av.w;
    Bs[lr][lk+0]=bv.x; Bs[lr][lk+1]=bv.y; Bs[lr][lk+2]=bv.z; Bs[lr][lk+3]=bv.w;
    __syncthreads();
#pragma unroll
    for (int kk = 0; kk < 16; ++kk) {
      float a0=As[ty*4+0][kk], a1=As[ty*4+1][kk], a2=As[ty*4+2][kk], a3=As[ty*4+3][kk];
      float b0=Bs[tx*4+0][kk], b1=Bs[tx*4+1][kk], b2=Bs[tx*4+2][kk], b3=Bs[tx*4+3][kk];
      acc[0][0]+=a0*b0; acc[0][1]+=a0*b1; acc[0][2]+=a0*b2; acc[0][3]+=a0*b3;
      acc[1][0]+=a1*b0; acc[1][1]+=a1*b1; acc[1][2]+=a1*b2; acc[1][3]+=a1*b3;
      acc[2][0]+=a2*b0; acc[2][1]+=a2*b1; acc[2][2]+=a2*b2; acc[2][3]+=a2*b3;
      acc[3][0]+=a3*b0; acc[3][1]+=a3*b1; acc[3][2]+=a3*b2; acc[3][3]+=a3*b3;
    }
    __syncthreads();
  }
  int row = rowBase + ty*4, col = colBase + tx*4;
#pragma unroll
  for (int i = 0; i < 4; ++i) {
    float aj[4] = {1.f,1.f,1.f,1.f};
    if (HASADJ) {
      float4 adjv = *(const float4*)&adj[(size_t)(row+i)*ldadj + col];
      aj[0]=adjv.x; aj[1]=adjv.y; aj[2]=adjv.z; aj[3]=adjv.w;
    }
    float v[4];
#pragma unroll
    for (int j = 0; j < 4; ++j) {
      float x = acc[i][j];
      if (HASBIAS) x += bias[col+j];
      if (HASADJ) x *= aj[j];
      if (RELU) x = fmaxf(x, 0.f);
      v[j] = x;
    }
    float* cp = &C[(size_t)(row+i)*ldc + col];   // 8B-aligned even at d_out+2
    *(float2*)cp = make_float2(v[0], v[1]);
    *(float2*)(cp+2) = make_float2(v[2], v[3]);
  }
}

// ---------------- row reduction: abs-sum (with eps floor) or mean ----------------
template<bool ABS>
__global__ void row_reduce(const float* __restrict__ W, int ld, int M,
                           float* __restrict__ out, float p /*eps or 1/M*/) {
  int n = blockIdx.x;
  const float* row = W + (size_t)n * ld;
  float s = 0;
  for (int m = threadIdx.x; m < M; m += 256) {
    float v = row[m];
    s += ABS ? fabsf(v) : v;
  }
  __shared__ float red[256];
  red[threadIdx.x] = s; __syncthreads();
  for (int k = 128; k > 0; k >>= 1) {
    if (threadIdx.x < k) red[threadIdx.x] += red[threadIdx.x + k];
    __syncthreads();
  }
  if (threadIdx.x == 0) out[n] = ABS ? fmaxf(red[0], p) : red[0] * p;
}

// ---------------- column mean, 2-stage ----------------
__global__ void colmean_part(const float* __restrict__ W, int ld, int rows_per,
                             float* __restrict__ part, int M) {
  int m = blockIdx.x * blockDim.x + threadIdx.x;
  int n0 = blockIdx.y * rows_per;
  float s = 0;
  for (int n = 0; n < rows_per; ++n) s += W[(size_t)(n0 + n) * ld + m];
  part[(size_t)blockIdx.y * M + m] = s;
}
__global__ void colmean_fin(const float* __restrict__ part, int M, int nparts,
                            float* __restrict__ out, float inv) {
  int m = blockIdx.x * blockDim.x + threadIdx.x;
  float s = 0;
  for (int k = 0; k < nparts; ++k) s += part[(size_t)k * M + m];
  out[m] = s * inv;
}

// ---------------- attn @ hs with K-split ----------------
__global__ __launch_bounds__(256) void attn_av(
    const float* __restrict__ attn, int ld,
    const float* __restrict__ hs, float* __restrict__ pt,
    int chunk, int N)
{
  int r0 = blockIdx.x * 32;
  int kc = blockIdx.y;
  int m0 = kc * chunk;
  __shared__ float Hs[32][DIM];
  __shared__ float As[32][33];
  int tid = threadIdx.x;
  int tx = tid & 31, ry = tid >> 5;
  float acc[4][4] = {};
  for (int mt = 0; mt < chunk; mt += 32) {
#pragma unroll
    for (int q = 0; q < 4; ++q) {
      int f = q * 256 + tid; int hr = f >> 5, hc = (f & 31) * 4;
      *(float4*)&Hs[hr][hc] = *(const float4*)&hs[(size_t)(m0 + mt + hr) * DIM + hc];
    }
    {
      int ar = tid >> 3, ac = (tid & 7) * 4;
      const float* src = &attn[(size_t)(r0 + ar) * ld + m0 + mt + ac];
      float2 u = *(const float2*)src; float2 w = *(const float2*)(src + 2);
      As[ar][ac] = u.x; As[ar][ac+1] = u.y; As[ar][ac+2] = w.x; As[ar][ac+3] = w.y;
    }
    __syncthreads();
#pragma unroll
    for (int mm = 0; mm < 32; ++mm) {
      float4 h4 = *(const float4*)&Hs[mm][tx * 4];
      float a0 = As[ry*4+0][mm], a1 = As[ry*4+1][mm], a2 = As[ry*4+2][mm], a3 = As[ry*4+3][mm];
      acc[0][0]+=a0*h4.x; acc[0][1]+=a0*h4.y; acc[0][2]+=a0*h4.z; acc[0][3]+=a0*h4.w;
      acc[1][0]+=a1*h4.x; acc[1][1]+=a1*h4.y; acc[1][2]+=a1*h4.z; acc[1][3]+=a1*h4.w;
      acc[2][0]+=a2*h4.x; acc[2][1]+=a2*h4.y; acc[2][2]+=a2*h4.z; acc[2][3]+=a2*h4.w;
      acc[3][0]+=a3*h4.x; acc[3][1]+=a3*h4.y; acc[3][2]+=a3*h4.z; acc[3][3]+=a3*h4.w;
    }
    __syncthreads();
  }
#pragma unroll
  for (int i = 0; i < 4; ++i) {
    float4 v = make_float4(acc[i][0], acc[i][1], acc[i][2], acc[i][3]);
    *(float4*)&pt[((size_t)kc * N + r0 + ry*4 + i) * DIM + tx*4] = v;
  }
}

// xs[n][d] += (sum_kc pt[kc][n][d]) / denom[n]
__global__ void axpy_reduce(const float* __restrict__ pt, const float* __restrict__ denom,
                            float* __restrict__ xs, int total) {
  int i = blockIdx.x * blockDim.x + threadIdx.x;
  if (i >= total) return;
  float s = 0;
#pragma unroll
  for (int k = 0; k < 8; ++k) s += pt[(size_t)k * total + i];
  xs[i] += s / denom[i >> 7];
}

__global__ void add_vec(const float* __restrict__ a, const float* __restrict__ b,
                        float* __restrict__ o, int n) {
  int i = blockIdx.x * blockDim.x + threadIdx.x;
  if (i < n) o[i] = a[i] + b[i];
}

// ---------------- bidirectional LSTM ----------------
// 512 thr = 8 waves. lane = 4*i + g : gate g of hidden index u = wave*16 + i.
// z-row rz = g*128 + u.  Gate gather via 3 shfl_down (same wave). h double-buffered
// in LDS -> ONE barrier/step. Wx software-pipelined (prefetch t+1 during step t).
__global__ __launch_bounds__(512) void lstm_kernel(
    const float* __restrict__ Whh,   // [2][512][128]
    const float* __restrict__ Wx,    // [2][M][512]  (x@Wih.T + bih + bhh precomputed)
    float* __restrict__ xs_rnn,      // [M][256]  (stores relu(h))
    int M)
{
  int dir = blockIdx.x;
  int tid = threadIdx.x;
  int w = tid >> 6, lane = tid & 63;
  int i = lane >> 2, g = lane & 3;
  int u = w * 16 + i;          // hidden index 0..127
  int rz = g * 128 + u;        // z row 0..511
  __shared__ float hbuf[2][DIM];
  float4 wreg[32];
  const float4* wrow = (const float4*)(Whh + ((size_t)dir * 512 + rz) * DIM);
#pragma unroll
  for (int r = 0; r < 32; ++r) wreg[r] = wrow[r];
  float c = 0.f;
  if (tid < DIM) hbuf[0][tid] = 0.f;
  __syncthreads();
  const float* WxD = Wx + (size_t)dir * M * 512;
  int t0 = dir ? (M - 1) : 0;
  float wx_cur = WxD[(size_t)t0 * 512 + rz];
  for (int s = 0; s < M; ++s) {
    int t = dir ? (M - 1 - s) : s;
    float wx_next = 0.f;
    if (s + 1 < M) {
      int tn = dir ? (M - 2 - s) : (s + 1);
      wx_next = WxD[(size_t)tn * 512 + rz];   // prefetch: latency hidden under dot
    }
    int cur = s & 1;
    const float4* h4p = (const float4*)hbuf[cur];
    float a0 = 0, a1 = 0, a2 = 0, a3 = 0;
#pragma unroll
    for (int r = 0; r < 32; ++r) {
      float4 h4 = h4p[r];                     // broadcast, conflict-free
      a0 += wreg[r].x * h4.x; a1 += wreg[r].y * h4.y;
      a2 += wreg[r].z * h4.z; a3 += wreg[r].w * h4.w;
    }
    float z = (a0 + a1) + (a2 + a3) + wx_cur;
    float zz = (g == 2) ? 2.f * z : z;        // tanh(z) = 2*sigmoid(2z)-1
    float sg = 1.f / (1.f + __expf(-zz));
    float av = (g == 2) ? 2.f * sg - 1.f : sg;
    float fv = __shfl_down(av, 1);
    float gv = __shfl_down(av, 2);
    float ov = __shfl_down(av, 3);
    if (g == 0) {                             // av = i-gate
      c = fv * c + av * gv;
      float e = __expf(-2.f * c);
      float th = (1.f - e) / (1.f + e);       // tanh(c)
      float hv = ov * th;
      hbuf[cur ^ 1][u] = hv;
      xs_rnn[(size_t)t * (2 * DIM) + dir * DIM + u] = fmaxf(hv, 0.f);
    }
    wx_cur = wx_next;
    __syncthreads();                          // single barrier per step
  }
}

// ---------------- weighted mean pooling ----------------
__global__ void pool_vec(const float* __restrict__ mat, const float* __restrict__ wv,
                         int n, float* __restrict__ out, float inv) {
  int t = threadIdx.x; int g = t >> 7, d = t & 127;
  float acc = 0;
  for (int r = g; r < n; r += 8) acc += wv[r] * mat[(size_t)r * DIM + d];
  __shared__ float red[1024];
  red[t] = acc; __syncthreads();
  if (g == 0) {
    float s = acc;
#pragma unroll
    for (int k = 1; k < 8; ++k) s += red[k * 128 + d];
    out[d] = s * inv;
  }
}

// ---------------- output MLP ----------------
__global__ void mlp_kernel(const float* __restrict__ cvec, const float* __restrict__ pvec,
                           const float* __restrict__ Wo, const float* __restrict__ bo,
                           const float* __restrict__ Wi, const float* __restrict__ bi,
                           float* __restrict__ out) {
  __shared__ float buf0[256], buf1[256];
  int t = threadIdx.x;
  buf0[t] = (t < 128) ? cvec[t] : pvec[t - 128];
  __syncthreads();
  {
    const float* W = Wo;                 // layer 0
    float s = bo[t];
    for (int v = 0; v < 256; ++v) s += W[t * 256 + v] * buf0[v];
    buf1[t] = fmaxf(s, 0.f);
  }
  __syncthreads();
  {
    const float* W = Wo + 256 * 256;     // layer 1
    float s = bo[256 + t];
    for (int v = 0; v < 256; ++v) s += W[t * 256 + v] * buf1[v];
    buf0[t] = fmaxf(s, 0.f);
  }
  __syncthreads();
  if (t < 2) {
    float s = bi[t];
    for (int v = 0; v < 256; ++v) s += Wi[t * 256 + v] * buf0[v];
    out[t] = s;
  }
}

extern "C" void kernel_launch(void* const* d_in, const int* in_sizes, int n_in,
                              void* d_out, int out_size, void* d_ws, size_t ws_size,
                              hipStream_t stream) {
  const int*   fingerprints = (const int*)d_in[0];
  const float* adjacency    = (const float*)d_in[1];
  const int*   words        = (const int*)d_in[2];
  const float* emb_fp       = (const float*)d_in[3];
  const float* emb_word     = (const float*)d_in[4];
  const float* Wg  = (const float*)d_in[5];
  const float* bg  = (const float*)d_in[6];
  const float* Wih = (const float*)d_in[7];
  const float* Whh = (const float*)d_in[8];
  const float* bih = (const float*)d_in[9];
  const float* bhh = (const float*)d_in[10];
  const float* Wc  = (const float*)d_in[11];
  const float* bc  = (const float*)d_in[12];
  const float* Wp  = (const float*)d_in[13];
  const float* bp  = (const float*)d_in[14];
  const float* Wo  = (const float*)d_in[15];
  const float* bo  = (const float*)d_in[16];
  const float* Wi  = (const float*)d_in[17];
  const float* bi  = (const float*)d_in[18];

  const int N = in_sizes[0];
  const int M = in_sizes[2];
  const int LGAT = in_sizes[5] / (DIM * DIM);

  float* out  = (float*)d_out;
  float* attn = out + 2;            // [N][M]: scratch during GAT, final `weights` at end

  float* ws = (float*)d_ws;
  size_t off = 0;
  auto alloc = [&](size_t nf) { float* p = ws + off; off += (nf + 3) & ~(size_t)3; return p; };
  float* xs     = alloc((size_t)N * DIM);
  float* hs     = alloc((size_t)N * DIM);
  float* wvb    = alloc((size_t)M * DIM);
  float* denom  = alloc(N);
  float* pt     = alloc((size_t)8 * N * DIM);    // K-split partials; aliased as Wx afterwards
  float* Wx     = pt;                            // [2][M][512]
  float* xs_rnn = alloc((size_t)M * 2 * DIM);
  float* hp     = alloc((size_t)M * DIM);
  float* hmat   = alloc((size_t)N * DIM);
  float* bsum   = alloc(1024);
  float* wcomp  = alloc(N);
  float* wprot  = alloc(M);
  float* cvec   = alloc(DIM);
  float* pvec   = alloc(DIM);
  float* cpart  = alloc((size_t)32 * M);
  (void)ws_size; (void)n_in; (void)out_size;

  // ---- embeddings ----
  gather_rows<<<(N * 32 + 255) / 256, 256, 0, stream>>>(emb_fp, fingerprints, xs, N);
  gather_rows<<<(M * 32 + 255) / 256, 256, 0, stream>>>(emb_word, words, wvb, M);

  // ---- GAT layers ----
  for (int l = 0; l < LGAT; ++l) {
    gemm_nt<true, true, false><<<dim3(DIM / 64, N / 64), 256, 0, stream>>>(
        xs, Wg + (size_t)l * DIM * DIM, hs, DIM, DIM, bg + l * DIM, nullptr, 0);
    gemm_nt<false, false, true><<<dim3(M / 64, N / 64), 256, 0, stream>>>(
        hs, hs, attn, M, DIM, nullptr, adjacency, M);
    row_reduce<true><<<N, 256, 0, stream>>>(attn, M, M, denom, 1e-12f);
    attn_av<<<dim3(N / 32, 8), 256, 0, stream>>>(attn, M, hs, pt, M / 8, N);
    axpy_reduce<<<(N * DIM) / 256, 256, 0, stream>>>(pt, denom, xs, N * DIM);
  }

  // ---- LSTM precompute + run ----
  add_vec<<<4, 256, 0, stream>>>(bih, bhh, bsum, 1024);
  for (int d = 0; d < 2; ++d) {
    gemm_nt<false, true, false><<<dim3(512 / 64, M / 64), 256, 0, stream>>>(
        wvb, Wih + (size_t)d * 512 * DIM, Wx + (size_t)d * M * 512, 512, DIM,
        bsum + d * 512, nullptr, 0);
  }
  lstm_kernel<<<2, 512, 0, stream>>>(Whh, Wx, xs_rnn, M);

  // ---- cross-attention pooling ----
  gemm_nt<true, true, false><<<dim3(DIM / 64, M / 64), 256, 0, stream>>>(
      xs_rnn, Wp, hp, DIM, 2 * DIM, bp, nullptr, 0);
  gemm_nt<true, true, false><<<dim3(DIM / 64, N / 64), 256, 0, stream>>>(
      xs, Wc, hmat, DIM, DIM, bc, nullptr, 0);
  gemm_nt<false, false, false><<<dim3(M / 64, N / 64), 256, 0, stream>>>(
      hmat, hp, attn, M, DIM, nullptr, nullptr, 0);   // final `weights` output
  row_reduce<false><<<N, 256, 0, stream>>>(attn, M, M, wcomp, 1.f / (float)M);
  colmean_part<<<dim3(M / 256, 32), 256, 0, stream>>>(attn, M, N / 32, cpart, M);
  colmean_fin<<<M / 256, 256, 0, stream>>>(cpart, M, 32, wprot, 1.f / (float)N);
  pool_vec<<<1, 1024, 0, stream>>>(hmat, wcomp, N, cvec, 1.f / (float)N);
  pool_vec<<<1, 1024, 0, stream>>>(hp, wprot, M, pvec, 1.f / (float)M);

  // ---- output MLP ----
  mlp_kernel<<<1, 256, 0, stream>>>(cvec, pvec, Wo, bo, Wi, bi, out);
}